// Round 6
// baseline (95.883 us; speedup 1.0000x reference)
//
#include <hip/hip_runtime.h>

namespace {

constexpr int kC = 32;
constexpr int kD = 512;
constexpr int kB = 512;
constexpr int kN = 1024;               // 2B rows (source ++ target)
constexpr int kCD = kC * kD;           // floats per batch index i
constexpr int TW = 64;                 // per-wave output tile (64x64)
constexpr int T2 = kN / TW;            // 16 tiles per side
constexpr int NP = T2 * (T2 + 1) / 2;  // 136 triangular pairs
constexpr int KSTEPS = kD / 32;        // 16 MFMA k-chunks

typedef float f32x4 __attribute__((ext_vector_type(4)));
typedef short s16x8 __attribute__((ext_vector_type(8)));

// pack two f32 to bf16 (RNE) into one u32: a -> low half, b -> high half
__device__ inline unsigned int pack_bf16(float a, float b) {
  unsigned int ua = __float_as_uint(a);
  unsigned int ub = __float_as_uint(b);
  ua += 0x7fffu + ((ua >> 16) & 1u);   // round-to-nearest-even
  ub += 0x7fffu + ((ub >> 16) & 1u);
  return (ua >> 16) | (ub & 0xffff0000u);
}

// Pass 1: tot[c][i][d] = bf16(total[i,c,d]); sq[c*kN+i] = sum_d total^2 (f32).
// One wave per (i,c) row of 512 floats. Also zeroes d_out (replaces memset).
__global__ void prep_kernel(const float* __restrict__ src,
                            const float* __restrict__ tgt,
                            float* __restrict__ sq,
                            unsigned int* __restrict__ tot,
                            float* __restrict__ out) {
  if (blockIdx.x == 0 && threadIdx.x == 0) *out = 0.f;
  int gw = (blockIdx.x * blockDim.x + threadIdx.x) >> 6;
  int lane = threadIdx.x & 63;
  int i = gw >> 5;
  int c = gw & 31;
  const float* p = (i < kB ? src + (size_t)i * kCD
                           : tgt + (size_t)(i - kB) * kCD) + c * kD;
  f32x4 v0 = *(const f32x4*)(p + lane * 8);
  f32x4 v1 = *(const f32x4*)(p + lane * 8 + 4);

  uint4 w = make_uint4(pack_bf16(v0.x, v0.y), pack_bf16(v0.z, v0.w),
                       pack_bf16(v1.x, v1.y), pack_bf16(v1.z, v1.w));
  *(uint4*)(tot + (size_t)(c * kN + i) * (kD / 2) + lane * 4) = w;

  float s = v0.x * v0.x + v0.y * v0.y + v0.z * v0.z + v0.w * v0.w
          + v1.x * v1.x + v1.y * v1.y + v1.z * v1.z + v1.w * v1.w;
#pragma unroll
  for (int o = 32; o > 0; o >>= 1) s += __shfl_down(s, o);
  if (lane == 0) sq[c * kN + i] = s;
}

// Pass 2: one INDEPENDENT wave per (pair(ti<=tj), c) 64x64 tile. No LDS
// staging, no per-step barriers: fragments gathered directly from L2-resident
// tot. Block = 4 waves of the same channel (4 consecutive pairs);
// b%8 == c%8 pins each channel's blocks to one XCD.
__launch_bounds__(256, 3)
__global__ void mmd_kernel(const unsigned short* __restrict__ tot,
                           const float* __restrict__ sq,
                           float* __restrict__ out) {
  const int b = blockIdx.x;
  const int c = b & 31;          // XCD pin
  const int pg = b >> 5;         // pair group, 0..33
  const int t = threadIdx.x;
  const int lane = t & 63;
  const int wid = t >> 6;

  int p = pg * 4 + wid;          // 0..135
  int ti = 0;
  while (p >= T2 - ti) { p -= T2 - ti; ++ti; }
  int tj = ti + p;

  const unsigned short* gA = tot + (size_t)(c * kN + ti * TW) * kD;
  const unsigned short* gB = tot + (size_t)(c * kN + tj * TW) * kD;

  // per-lane fragment base: row (lane&15), k-chunk (lane>>4)*8 elements
  const int loff = (lane & 15) * kD + (lane >> 4) * 8;

  // 8 precomputed base pointers -> every load folds ks into a 13-bit imm
  const s16x8* aB[4];
  const s16x8* bB[4];
#pragma unroll
  for (int m = 0; m < 4; ++m) {
    aB[m] = (const s16x8*)(gA + (size_t)m * 16 * kD + loff);
    bB[m] = (const s16x8*)(gB + (size_t)m * 16 * kD + loff);
  }

  f32x4 acc[4][4] = {};

#pragma unroll
  for (int ks = 0; ks < KSTEPS; ++ks) {
    s16x8 aF[4], bF[4];
#pragma unroll
    for (int m = 0; m < 4; ++m) aF[m] = aB[m][ks * 4];   // +ks*64 bytes
#pragma unroll
    for (int n = 0; n < 4; ++n) bF[n] = bB[n][ks * 4];
#pragma unroll
    for (int m = 0; m < 4; ++m)
#pragma unroll
      for (int n = 0; n < 4; ++n)
        acc[m][n] = __builtin_amdgcn_mfma_f32_16x16x32_bf16(
            aF[m], bF[n], acc[m][n], 0, 0, 0);
  }

  // epilogue: L2 = sq_i + sq_j - 2*cross; 5-sigma kernel via repeated squaring
  const float sA = (ti < T2 / 2) ? 1.f : -1.f;
  const float sB = (tj < T2 / 2) ? 1.f : -1.f;
  const float scale = sA * sB * ((ti == tj) ? 1.f : 2.f) / 262144.f;  // /B^2
  const float* sqA = sq + c * kN + ti * TW;
  const float* sqB = sq + c * kN + tj * TW;

  float local = 0.f;
#pragma unroll
  for (int m = 0; m < 4; ++m) {
    float sqa_r[4];
#pragma unroll
    for (int rI = 0; rI < 4; ++rI)
      sqa_r[rI] = sqA[m * 16 + (lane >> 4) * 4 + rI];
#pragma unroll
    for (int n = 0; n < 4; ++n) {
      float sqb_ = sqB[n * 16 + (lane & 15)];
#pragma unroll
      for (int rI = 0; rI < 4; ++rI) {
        float L2 = sqa_r[rI] + sqb_ - 2.f * acc[m][n][rI];
        float tt = __expf(L2 * -0.0625f);  // exp(-L2/16)
        float t2 = tt * tt, t4 = t2 * t2, t8 = t4 * t4;
        local += tt + t2 + t4 + t8 + t8 * t8;
      }
    }
  }
  local *= scale;   // per-wave scale (ti,tj differ across waves in a block)

  __shared__ float wsum[4];
#pragma unroll
  for (int o = 32; o > 0; o >>= 1) local += __shfl_down(local, o);
  if (lane == 0) wsum[wid] = local;
  __syncthreads();
  if (t == 0)
    atomicAdd(out, wsum[0] + wsum[1] + wsum[2] + wsum[3]);
}

}  // namespace

extern "C" void kernel_launch(void* const* d_in, const int* in_sizes, int n_in,
                              void* d_out, int out_size, void* d_ws,
                              size_t ws_size, hipStream_t stream) {
  const float* src = (const float*)d_in[0];
  const float* tgt = (const float*)d_in[1];
  float* out = (float*)d_out;

  // workspace: [sq: 32*1024 f32 = 128 KiB][tot bf16: 32*1024*512*2B = 32 MiB]
  float* sq = (float*)d_ws;
  unsigned int* tot = (unsigned int*)((char*)d_ws + (size_t)kC * kN * 4);

  {
    int blocks = (kN * kC) / 4;   // one wave per (i,c) row, 4 waves/block
    prep_kernel<<<blocks, 256, 0, stream>>>(src, tgt, sq, tot, out);
  }
  {
    int blocks = NP * kC / 4;     // 136 pairs x 32 ch, 4 waves/block = 1088
    mmd_kernel<<<blocks, 256, 0, stream>>>((const unsigned short*)tot, sq, out);
  }
}

// Round 7
// 62.879 us; speedup vs baseline: 1.5249x; 1.5249x over previous
//
#include <hip/hip_runtime.h>

namespace {

constexpr int kC = 32;
constexpr int kD = 512;
constexpr int kB = 512;
constexpr int kN = 1024;               // 2B rows (source ++ target)
constexpr int kCD = kC * kD;           // floats per batch index i
constexpr int BM = 256;                // block tile (256x256)
constexpr int BKt = 32;                // K-tile (bf16 elements)
constexpr int KT = kD / BKt;           // 16 K-tiles
constexpr int T2 = kN / BM;            // 4 tiles per side
constexpr int NP = T2 * (T2 + 1) / 2;  // 10 triangular pairs

typedef float f32x4 __attribute__((ext_vector_type(4)));
typedef short s16x8 __attribute__((ext_vector_type(8)));

// pack two f32 to bf16 (RNE) into one u32: a -> low half, b -> high half
__device__ inline unsigned int pack_bf16(float a, float b) {
  unsigned int ua = __float_as_uint(a);
  unsigned int ub = __float_as_uint(b);
  ua += 0x7fffu + ((ua >> 16) & 1u);   // round-to-nearest-even
  ub += 0x7fffu + ((ub >> 16) & 1u);
  return (ua >> 16) | (ub & 0xffff0000u);
}

// Pass 1: tot[c][i][d] = bf16(total[i,c,d]); sq[c*kN+i] = sum_d total^2 (f32).
// One wave per (i,c) row of 512 floats. Also zeroes d_out (replaces memset).
__global__ void prep_kernel(const float* __restrict__ src,
                            const float* __restrict__ tgt,
                            float* __restrict__ sq,
                            unsigned int* __restrict__ tot,
                            float* __restrict__ out) {
  if (blockIdx.x == 0 && threadIdx.x == 0) *out = 0.f;
  int gw = (blockIdx.x * blockDim.x + threadIdx.x) >> 6;
  int lane = threadIdx.x & 63;
  int i = gw >> 5;
  int c = gw & 31;
  const float* p = (i < kB ? src + (size_t)i * kCD
                           : tgt + (size_t)(i - kB) * kCD) + c * kD;
  f32x4 v0 = *(const f32x4*)(p + lane * 8);
  f32x4 v1 = *(const f32x4*)(p + lane * 8 + 4);

  uint4 w = make_uint4(pack_bf16(v0.x, v0.y), pack_bf16(v0.z, v0.w),
                       pack_bf16(v1.x, v1.y), pack_bf16(v1.z, v1.w));
  *(uint4*)(tot + (size_t)(c * kN + i) * (kD / 2) + lane * 4) = w;

  float s = v0.x * v0.x + v0.y * v0.y + v0.z * v0.z + v0.w * v0.w
          + v1.x * v1.x + v1.y * v1.y + v1.z * v1.z + v1.w * v1.w;
#pragma unroll
  for (int o = 32; o > 0; o >>= 1) s += __shfl_down(s, o);
  if (lane == 0) sq[c * kN + i] = s;
}

// Pass 2: 256x256 triangular tile per block, 8 waves (2x4) of 128x64 each.
// Phase-split K-loop (2 MFMA phases per 32-wide K-tile), 3-deep LDS buffers,
// stage-ahead-2 with counted vmcnt(4) at tile seams (T3+T4), setprio (T5).
// LDS layout per 16KB buffer: row r (0..255, 64B), 16B chunk c (0..3) at byte
// S(r,c) = (r>>1)*128 + (r&1)*64 + (c ^ ((r>>1)&3))*16  [R4/R5-verified].
__launch_bounds__(512, 2)
__global__ void mmd_kernel(const unsigned short* __restrict__ tot,
                           const float* __restrict__ sq,
                           float* __restrict__ out) {
  const int b = blockIdx.x;
  const int c = b & 31;          // b = pair*32 + c -> b%8 == c%8 (XCD pin)
  int p = b >> 5;                // 0..9
  int ti = 0;
  while (p >= T2 - ti) { p -= T2 - ti; ++ti; }
  int tj = ti + p;

  __shared__ __align__(16) unsigned short lA[3][BM * BKt];  // 3 x 16KB
  __shared__ __align__(16) unsigned short lB[3][BM * BKt];
  __shared__ float wsum[8];

  const int t = threadIdx.x;
  const int lane = t & 63;
  const int wid = t >> 6;        // 0..7
  const int wr = wid >> 2;       // wave row-half (0..1): rows wr*128..+127
  const int wcn = wid & 3;       // wave col (0..3): cols wcn*64..+63

  const unsigned short* gA = tot + (size_t)(c * kN + ti * BM) * kD;
  const unsigned short* gB = tot + (size_t)(c * kN + tj * BM) * kD;

  // staging: instr i (0..15) covers LDS bytes [i*1024,+1024); lane l's 16B at
  // linear i*1024+l*16 holds global row 16i+srow, chunk scch (both lane-only):
  const int srow = ((lane >> 3) << 1) + ((lane >> 2) & 1);
  const int scch = (lane & 3) ^ ((lane >> 3) & 3);

  auto STAGE_A = [&](int buf, int kt) {
#pragma unroll
    for (int q = 0; q < 2; ++q) {
      int i = wid * 2 + q;
      int r = 16 * i + srow;
      const unsigned short* s = gA + (size_t)r * kD + kt * BKt + scch * 8;
      __builtin_amdgcn_global_load_lds(
          (const __attribute__((address_space(1))) unsigned int*)s,
          (__attribute__((address_space(3))) unsigned int*)&lA[buf][i * 512],
          16, 0, 0);
    }
  };
  auto STAGE_B = [&](int buf, int kt) {
#pragma unroll
    for (int q = 0; q < 2; ++q) {
      int i = wid * 2 + q;
      int r = 16 * i + srow;
      const unsigned short* s = gB + (size_t)r * kD + kt * BKt + scch * 8;
      __builtin_amdgcn_global_load_lds(
          (const __attribute__((address_space(1))) unsigned int*)s,
          (__attribute__((address_space(3))) unsigned int*)&lB[buf][i * 512],
          16, 0, 0);
    }
  };

  // fragment-read lane offset (bytes) within a tile: row 16m + (lane&15),
  // k-chunk (lane>>4); swizzle term depends only on lane -> m*1024 imm.
  const int l15 = lane & 15;
  const int s4 = lane >> 4;
  const int laneoff = ((l15 >> 1) << 7) + ((l15 & 1) << 6) +
                      ((s4 ^ ((l15 >> 1) & 3)) << 4);

  f32x4 acc[8][4] = {};

  // prologue: stage tiles 0 and 1
  STAGE_A(0, 0); STAGE_B(0, 0);
  STAGE_A(1, 1); STAGE_B(1, 1);
  asm volatile("s_waitcnt vmcnt(4)" ::: "memory");   // tile 0 resident
  __builtin_amdgcn_sched_barrier(0);
  __builtin_amdgcn_s_barrier();

#pragma unroll
  for (int kt = 0; kt < KT; ++kt) {
    const int buf = kt % 3;
    const char* Abase = (const char*)lA[buf] + wr * 8192 + laneoff;
    const char* Bbase = (const char*)lB[buf] + wcn * 4096 + laneoff;

    s16x8 aF[4], bF[4];
    // ---- phase 0: m=0..3 x n=0..3 ----
#pragma unroll
    for (int m = 0; m < 4; ++m) aF[m] = *(const s16x8*)(Abase + m * 1024);
#pragma unroll
    for (int n = 0; n < 4; ++n) bF[n] = *(const s16x8*)(Bbase + n * 1024);
    if (kt + 2 < KT) STAGE_A((kt + 2) % 3, kt + 2);
    __builtin_amdgcn_sched_barrier(0);
    __builtin_amdgcn_s_barrier();
    asm volatile("s_waitcnt lgkmcnt(0)" ::: "memory");
    __builtin_amdgcn_sched_barrier(0);
    __builtin_amdgcn_s_setprio(1);
#pragma unroll
    for (int m = 0; m < 4; ++m)
#pragma unroll
      for (int n = 0; n < 4; ++n)
        acc[m][n] = __builtin_amdgcn_mfma_f32_16x16x32_bf16(
            aF[m], bF[n], acc[m][n], 0, 0, 0);
    __builtin_amdgcn_s_setprio(0);
    __builtin_amdgcn_sched_barrier(0);
    __builtin_amdgcn_s_barrier();

    // ---- phase 1: m=4..7 x n=0..3 (bF reused) ----
#pragma unroll
    for (int m = 0; m < 4; ++m)
      aF[m] = *(const s16x8*)(Abase + (m + 4) * 1024);
    if (kt + 2 < KT) STAGE_B((kt + 2) % 3, kt + 2);
    __builtin_amdgcn_sched_barrier(0);
    __builtin_amdgcn_s_barrier();
    asm volatile("s_waitcnt lgkmcnt(0)" ::: "memory");
    __builtin_amdgcn_sched_barrier(0);
    __builtin_amdgcn_s_setprio(1);
#pragma unroll
    for (int m = 0; m < 4; ++m)
#pragma unroll
      for (int n = 0; n < 4; ++n)
        acc[m + 4][n] = __builtin_amdgcn_mfma_f32_16x16x32_bf16(
            aF[m], bF[n], acc[m + 4][n], 0, 0, 0);
    __builtin_amdgcn_s_setprio(0);

    // tile seam: guarantee tile kt+1 resident after the barrier; keep tile
    // kt+2's 4 loads in flight (T4: never vmcnt(0) mid-loop).
    if (kt < KT - 2) asm volatile("s_waitcnt vmcnt(4)" ::: "memory");
    else if (kt == KT - 2) asm volatile("s_waitcnt vmcnt(0)" ::: "memory");
    __builtin_amdgcn_sched_barrier(0);
    __builtin_amdgcn_s_barrier();
  }

  // epilogue: L2 = sq_i + sq_j - 2*cross; 5-sigma kernel via repeated squaring
  const float sA = (ti < T2 / 2) ? 1.f : -1.f;
  const float sB = (tj < T2 / 2) ? 1.f : -1.f;
  const float scale = sA * sB * ((ti == tj) ? 1.f : 2.f) / 262144.f;  // /B^2
  const float* sqA = sq + c * kN + ti * BM + wr * 128;
  const float* sqB = sq + c * kN + tj * BM + wcn * 64;

  float local = 0.f;
#pragma unroll
  for (int m = 0; m < 8; ++m) {
    float sqa_r[4];
#pragma unroll
    for (int rI = 0; rI < 4; ++rI)
      sqa_r[rI] = sqA[m * 16 + (lane >> 4) * 4 + rI];
#pragma unroll
    for (int n = 0; n < 4; ++n) {
      float sqb_ = sqB[n * 16 + (lane & 15)];
#pragma unroll
      for (int rI = 0; rI < 4; ++rI) {
        float L2 = sqa_r[rI] + sqb_ - 2.f * acc[m][n][rI];
        float tt = __expf(L2 * -0.0625f);  // exp(-L2/16)
        float t2 = tt * tt, t4 = t2 * t2, t8 = t4 * t4;
        local += tt + t2 + t4 + t8 + t8 * t8;
      }
    }
  }
  local *= scale;

#pragma unroll
  for (int o = 32; o > 0; o >>= 1) local += __shfl_down(local, o);
  if (lane == 0) wsum[wid] = local;
  __syncthreads();
  if (t == 0) {
    float s = 0.f;
#pragma unroll
    for (int w = 0; w < 8; ++w) s += wsum[w];
    atomicAdd(out, s);
  }
}

}  // namespace

extern "C" void kernel_launch(void* const* d_in, const int* in_sizes, int n_in,
                              void* d_out, int out_size, void* d_ws,
                              size_t ws_size, hipStream_t stream) {
  const float* src = (const float*)d_in[0];
  const float* tgt = (const float*)d_in[1];
  float* out = (float*)d_out;

  // workspace: [sq: 32*1024 f32 = 128 KiB][tot bf16: 32*1024*512*2B = 32 MiB]
  float* sq = (float*)d_ws;
  unsigned int* tot = (unsigned int*)((char*)d_ws + (size_t)kC * kN * 4);

  {
    int blocks = (kN * kC) / 4;   // one wave per (i,c) row, 4 waves/block
    prep_kernel<<<blocks, 256, 0, stream>>>(src, tgt, sq, tot, out);
  }
  {
    int blocks = NP * kC;         // 10 pairs x 32 channels = 320
    mmd_kernel<<<blocks, 512, 0, stream>>>((const unsigned short*)tot, sq, out);
  }
}